// Round 1
// 75.441 us; speedup vs baseline: 1.0040x; 1.0040x over previous
//
#include <hip/hip_runtime.h>

#define NUM_STEPS 25
#define THREADS 256

// One thread per sample (B = 32768). The 3->30->30->3->2 MLP + softmax on a
// 3-bit spike vector collapses to an 8-entry float2 LUT. The 25-step LIF loop
// accumulates a bit-sliced histogram (8 patterns x 8-bit counters in one
// uint64; max count 150 < 256), so the hot loop touches no memory.
//
// v2 (latency-hiding restructure): the harness re-poisons a 256 MiB buffer
// every iteration, evicting all caches, so every weight load is cold HBM
// (~900 cyc). All weight loads are therefore ISSUED into registers before the
// LIF loop and CONSUMED after it — the pure-ALU loop hides the load latency.
// The four sync-separated MLP phases move after the loop (registers only +
// LDS), shrinking the pre-loop critical path to "stage x + 1 barrier".
__global__ __launch_bounds__(THREADS) void snn_lut_kernel(
    const float* __restrict__ x,
    const float* __restrict__ W1, const float* __restrict__ b1,
    const float* __restrict__ W2, const float* __restrict__ b2,
    const float* __restrict__ W3, const float* __restrict__ b3,
    const float* __restrict__ W4, const float* __restrict__ b4,
    float* __restrict__ out, int B)
{
    __shared__ float h1s[8][30];
    __shared__ float h2s[8][32];          // +2 pad keeps rows bank-shifted
    __shared__ float h3s[8][3];
    __shared__ float2 lut[8];
    __shared__ float xs[THREADS * 9];     // staged x, conflict-free access

    const int tid = threadIdx.x;
    const int blk0 = blockIdx.x * THREADS;

    // ---- Coalesced stage of x: stride-1 global loads -> LDS ----
    {
        const float* xb = x + (size_t)blk0 * 9;
        #pragma unroll
        for (int k = 0; k < 9; ++k) {
            const int i = tid + k * THREADS;           // contiguous across lanes
            xs[i] = xb[i];
        }
    }

    // ---- Issue ALL weight loads now; consume only after the LIF loop. ----
    // Work-item mapping (same as the post-loop phases):
    //   tid < 240 : layer-1/2 unit  (p = pattern 0..7, h = hidden 0..29)
    //   tid < 24  : layer-3 unit    (p3 = pattern, h3 = output 0..2)
    //   tid < 8   : layer-4/softmax (pattern = tid)
    const int p  = tid / 30, h  = tid - p * 30;
    const int p3 = tid / 3,  h3 = tid - p3 * 3;

    float w1r[3], b1v, b2v, w2r[30];
    if (tid < 240) {
        w1r[0] = W1[h * 3 + 0];
        w1r[1] = W1[h * 3 + 1];
        w1r[2] = W1[h * 3 + 2];
        b1v = b1[h];
        b2v = b2[h];
        #pragma unroll
        for (int k = 0; k < 30; ++k) w2r[k] = W2[h * 30 + k];
    }
    float w3r[30], b3v;
    if (tid < 24) {
        b3v = b3[h3];
        #pragma unroll
        for (int k = 0; k < 30; ++k) w3r[k] = W3[h3 * 30 + k];
    }
    float w4r[6], b4r[2];
    if (tid < 8) {
        #pragma unroll
        for (int k = 0; k < 6; ++k) w4r[k] = W4[k];   // [0..2]=row0, [3..5]=row1
        b4r[0] = b4[0];
        b4r[1] = b4[1];
    }

    __syncthreads();                                   // xs visible

    // ---- Per-sample LIF recurrence, histogram accumulation (no memory) ----
    float xv[9], m[9], r[9];
    #pragma unroll
    for (int c = 0; c < 9; ++c) {
        xv[c] = xs[tid * 9 + c];   // stride 9 across lanes: gcd(9,32)=1 -> 2-way max (free)
        m[c] = 0.0f;
        r[c] = 0.0f;
    }

    unsigned long long hist = 0ULL;
    for (int t = 0; t < NUM_STEPS; ++t) {
        int s[9];
        #pragma unroll
        for (int c = 0; c < 9; ++c) {
            // Exact left-to-right fp32 ops (no FMA contraction) so the
            // > 1.0 spike decisions match the numpy reference bit-for-bit.
            m[c] = __fsub_rn(__fadd_rn(__fmul_rn(0.95f, m[c]), xv[c]), r[c]);
            const bool sp = m[c] > 1.0f;
            s[c] = sp ? 1 : 0;
            r[c] = sp ? 1.0f : 0.0f;   // this spike is next step's reset
        }
        // rows of the 3x3 grid
        const int p0 = s[0] | (s[1] << 1) | (s[2] << 2);
        const int p1 = s[3] | (s[4] << 1) | (s[5] << 2);
        const int p2 = s[6] | (s[7] << 1) | (s[8] << 2);
        // cols (swapaxes): bit k of col j is spk[3k + j]
        const int p3b = s[0] | (s[3] << 1) | (s[6] << 2);
        const int p4b = s[1] | (s[4] << 1) | (s[7] << 2);
        const int p5b = s[2] | (s[5] << 1) | (s[8] << 2);

        hist += (1ULL << (p0 << 3)) + (1ULL << (p1 << 3)) + (1ULL << (p2 << 3))
              + (1ULL << (p3b << 3)) + (1ULL << (p4b << 3)) + (1ULL << (p5b << 3));
    }

    // ---- Post-loop MLP -> LUT (weights already resident in registers) ----
    if (tid < 240) {
        const float i0 = (float)(p & 1);
        const float i1 = (float)((p >> 1) & 1);
        const float i2 = (float)((p >> 2) & 1);
        float v = w1r[0] * i0 + w1r[1] * i1 + w1r[2] * i2 + b1v;
        h1s[p][h] = fmaxf(v, 0.0f);
    }
    __syncthreads();
    if (tid < 240) {
        float v = b2v;
        #pragma unroll
        for (int k = 0; k < 30; ++k) v += w2r[k] * h1s[p][k];
        h2s[p][h] = fmaxf(v, 0.0f);
    }
    __syncthreads();
    if (tid < 24) {
        float v = b3v;
        #pragma unroll
        for (int k = 0; k < 30; ++k) v += w3r[k] * h2s[p3][k];
        h3s[p3][h3] = fmaxf(v, 0.0f);
    }
    __syncthreads();
    if (tid < 8) {
        float o0 = b4r[0] + w4r[0] * h3s[tid][0] + w4r[1] * h3s[tid][1] + w4r[2] * h3s[tid][2];
        float o1 = b4r[1] + w4r[3] * h3s[tid][0] + w4r[4] * h3s[tid][1] + w4r[5] * h3s[tid][2];
        o0 = fmaxf(o0, 0.0f);
        o1 = fmaxf(o1, 0.0f);
        const float e0 = expf(o0), e1 = expf(o1);
        const float inv = 1.0f / (e0 + e1);
        lut[tid] = make_float2(e0 * inv, e1 * inv);
    }
    __syncthreads();                                   // lut visible

    float acc0 = 0.0f, acc1 = 0.0f;
    #pragma unroll
    for (int q = 0; q < 8; ++q) {
        const float cnt = (float)((hist >> (q << 3)) & 0xFFULL);
        const float2 l = lut[q];                       // broadcast, no conflict
        acc0 += cnt * l.x;
        acc1 += cnt * l.y;
    }

    const int b = blk0 + tid;
    if (b < B) {
        reinterpret_cast<float2*>(out)[b] = make_float2(acc0, acc1);
    }
}

extern "C" void kernel_launch(void* const* d_in, const int* in_sizes, int n_in,
                              void* d_out, int out_size, void* d_ws, size_t ws_size,
                              hipStream_t stream) {
    const float* x  = (const float*)d_in[0];
    const float* W1 = (const float*)d_in[1];
    const float* b1 = (const float*)d_in[2];
    const float* W2 = (const float*)d_in[3];
    const float* b2 = (const float*)d_in[4];
    const float* W3 = (const float*)d_in[5];
    const float* b3 = (const float*)d_in[6];
    const float* W4 = (const float*)d_in[7];
    const float* b4 = (const float*)d_in[8];
    float* out = (float*)d_out;

    const int B = in_sizes[0] / 9;
    const int blocks = (B + THREADS - 1) / THREADS;
    snn_lut_kernel<<<blocks, THREADS, 0, stream>>>(
        x, W1, b1, W2, b2, W3, b3, W4, b4, out, B);
}